// Round 6
// baseline (185.313 us; speedup 1.0000x reference)
//
#include <hip/hip_runtime.h>
#include <math.h>

// Problem constants (from reference)
#define N_NODES 10000
#define K_NB    32
#define D       256    // per-group input/output feature dim
#define XD      512    // x / t / out row stride (2 groups concatenated)

typedef __attribute__((ext_vector_type(8))) short  short8;  // 8 bf16 (4 VGPR) MFMA A/B frag
typedef __attribute__((ext_vector_type(4))) float  f32x4;   // MFMA C/D frag

__device__ __forceinline__ float clip1(float v) { return fminf(fmaxf(v, -1.f), 1.f); }

__device__ __forceinline__ unsigned int bf16_rne(float f) {   // RNE f32 -> bf16 bits
    unsigned int u = __float_as_uint(f);
    return (u + 0x7FFFu + ((u >> 16) & 1u)) >> 16;
}
__device__ __forceinline__ float bf16f(unsigned int h) { return __uint_as_float(h << 16); }

// 8 consecutive-k fp32 -> hi/lo bf16 (Markidis split), packed for ds_write_b128
__device__ __forceinline__ void cvt8(float4 A, float4 B, uint4& hi, uint4& lo) {
    const float v[8] = {A.x, A.y, A.z, A.w, B.x, B.y, B.z, B.w};
    unsigned int h[8], q[8];
    #pragma unroll
    for (int i = 0; i < 8; ++i) {
        h[i] = bf16_rne(v[i]);
        q[i] = bf16_rne(v[i] - bf16f(h[i]));
    }
    hi = make_uint4(h[0] | (h[1] << 16), h[2] | (h[3] << 16),
                    h[4] | (h[5] << 16), h[6] | (h[7] << 16));
    lo = make_uint4(q[0] | (q[1] << 16), q[2] | (q[3] << 16),
                    q[4] | (q[5] << 16), q[6] | (q[7] << 16));
}

// Kernel 1: t[row][g*256+o] = clip( (x_g @ W^T)[row][o] * softmax(a)[o], -1, 1 )
// Split-precision bf16 MFMA GEMM: x = xh+xl, W = wh+wl (bf16 each);
// out ~= xh*wh + xl*wh + xh*wl  (xl*wl ~ 2^-32, dropped) -> ~fp32 precision.
// Block = 256 thr = 4 waves; block owns 64 rows (wave w: rows m0+16w..+15),
// all 256 output cols (16 n-tiles of 16), K looped in 8 chunks of 32.
// W chunk-slab is converted once/block/chunk into LDS in MFMA-FRAGMENT order:
// frag (nt, lane) 16B at dword idx (nt*64+lane)*4 -> ds_read_b128 lane-seq,
// conflict-free.  k-slot map (k = 8*(lane>>4)+e) identical for A and B ->
// any consistent slot bijection contracts correctly; C/D map is the m89-
// verified col=lane&15, row=(lane>>4)*4+reg.
__global__ __launch_bounds__(256, 2)
void gemm_mfma(const float* __restrict__ x,
               const float* __restrict__ W1, const float* __restrict__ a1,
               const float* __restrict__ W2, const float* __restrict__ a2,
               float* __restrict__ t)
{
    const int g = blockIdx.y;
    const float* __restrict__ W = g ? W2 : W1;
    const float* __restrict__ a = g ? a2 : a1;
    const int m0  = blockIdx.x * 64;
    const int tid = threadIdx.x;
    const int w   = tid >> 6;
    const int l   = tid & 63;

    __shared__ unsigned int Whi[16 * 64 * 4];   // 16 KB, fragment-ordered bf16-hi
    __shared__ unsigned int Wlo[16 * 64 * 4];   // 16 KB, bf16-lo
    __shared__ float fwL[D];
    __shared__ float red[16];

    // ---- softmax(a) over 256 (block == 256 threads), redundantly per block ----
    {
        float v = a[tid];
        float m = v;
        #pragma unroll
        for (int o = 32; o; o >>= 1) m = fmaxf(m, __shfl_xor(m, o));
        if ((tid & 63) == 0) red[tid >> 6] = m;
        __syncthreads();
        m = fmaxf(fmaxf(red[0], red[1]), fmaxf(red[2], red[3]));
        float e = expf(v - m);
        float s = e;
        #pragma unroll
        for (int o = 32; o; o >>= 1) s += __shfl_xor(s, o);
        if ((tid & 63) == 0) red[4 + (tid >> 6)] = s;
        __syncthreads();
        s = red[4] + red[5] + red[6] + red[7];
        fwL[tid] = e / s;
    }

    f32x4 acc[16];
    #pragma unroll
    for (int i = 0; i < 16; ++i) acc[i] = (f32x4){0.f, 0.f, 0.f, 0.f};

    const int arow = m0 + w * 16 + (l & 15);      // this lane's A row
    const int koff = 8 * (l >> 4);                // this lane's k-slot base

    for (int kc = 0; kc < 8; ++kc) {
        __syncthreads();
        // ---- stage W[., kc*32..+31] -> fragment-ordered bf16 hi/lo LDS ----
        {
            const int r = tid;                    // one thread per W row
            const float* wp = &W[(size_t)r * D + kc * 32];
            float4 f[8];
            #pragma unroll
            for (int j = 0; j < 8; ++j) f[j] = *(const float4*)&wp[4 * j];
            #pragma unroll
            for (int s = 0; s < 4; ++s) {         // lane-group s covers k 8s..8s+7
                uint4 hi, lo;
                cvt8(f[2 * s], f[2 * s + 1], hi, lo);
                const int idx = (((r >> 4) * 64) + (r & 15) + 16 * s) * 4;
                *(uint4*)&Whi[idx] = hi;
                *(uint4*)&Wlo[idx] = lo;
            }
        }
        __syncthreads();

        // ---- A fragment: 8 consecutive k fp32 -> hi/lo bf16 ----
        float4 xa = make_float4(0.f, 0.f, 0.f, 0.f), xb = xa;
        if (arow < N_NODES) {
            const float* xp = &x[(size_t)arow * XD + g * D + kc * 32 + koff];
            xa = *(const float4*)&xp[0];
            xb = *(const float4*)&xp[4];
        }
        uint4 ahi, alo;
        cvt8(xa, xb, ahi, alo);
        const short8 ah = __builtin_bit_cast(short8, ahi);
        const short8 al = __builtin_bit_cast(short8, alo);

        #pragma unroll
        for (int nt = 0; nt < 16; ++nt) {
            const short8 bh = __builtin_bit_cast(short8, *(const uint4*)&Whi[(nt * 64 + l) * 4]);
            const short8 bl = __builtin_bit_cast(short8, *(const uint4*)&Wlo[(nt * 64 + l) * 4]);
            acc[nt] = __builtin_amdgcn_mfma_f32_16x16x32_bf16(ah, bh, acc[nt], 0, 0, 0);
            acc[nt] = __builtin_amdgcn_mfma_f32_16x16x32_bf16(al, bh, acc[nt], 0, 0, 0);
            acc[nt] = __builtin_amdgcn_mfma_f32_16x16x32_bf16(ah, bl, acc[nt], 0, 0, 0);
        }
    }

    // ---- epilogue: fw scale + hardtanh + store (C/D: col=l&15, row=(l>>4)*4+r) ----
    #pragma unroll
    for (int nt = 0; nt < 16; ++nt) {
        const int   col = nt * 16 + (l & 15);
        const float fw  = fwL[col];
        #pragma unroll
        for (int r = 0; r < 4; ++r) {
            const int row = m0 + w * 16 + (l >> 4) * 4 + r;
            if (row < N_NODES)
                t[(size_t)row * XD + g * D + col] = clip1(acc[nt][r] * fw);
        }
    }
}

// Kernel 2: ONE WAVE per (n,g) — zero LDS, zero barriers.
//   out_n = sum_k exp(-d2_k) * nb_k / sum_k exp(-d2_k)
// (identical math to reference softmax; max-subtract dropped since t is
// softmax(a)-feature-scaled -> d2 ~ 0.02 << 88, no underflow possible).
// Wave loops 4 chunks x 8 batched gathers; d2 butterfly-reduced over 64 lanes
// (uniform), e/S stay lane-uniform, aggregation in registers, float4 store.
// grid 5000, block 256 = 4 independent waves (ids blockIdx*4 + wave).
__global__ __launch_bounds__(256, 6)
void gat_aggregate(const float* __restrict__ t, const int* __restrict__ graph,
                   float* __restrict__ out)
{
    const int id = blockIdx.x * 4 + (threadIdx.x >> 6);   // (n,g) pair, 0..19999
    const int n  = id >> 1;
    const int g  = id & 1;
    const int l  = threadIdx.x & 63;

    const int    ridx = graph[(size_t)n * K_NB + (l & 31)];   // lane's neighbor idx
    const size_t gcol = (size_t)g * D + 4 * l;
    const float4 own4 = *(const float4*)&t[(size_t)n * XD + gcol];

    float4 p = make_float4(0.f, 0.f, 0.f, 0.f);
    float  S = 0.f;

    #pragma unroll
    for (int c = 0; c < 4; ++c) {
        // batch 8 gathers before any use (8 outstanding float4/lane)
        float4 nb[8];
        #pragma unroll
        for (int kk = 0; kk < 8; ++kk) {
            const int row = __shfl(ridx, c * 8 + kk);     // broadcast from lane
            nb[kk] = *(const float4*)&t[(size_t)row * XD + gcol];
        }
        #pragma unroll
        for (int kk = 0; kk < 8; ++kk) {
            const float dx = own4.x - nb[kk].x, dy = own4.y - nb[kk].y;
            const float dz = own4.z - nb[kk].z, dw = own4.w - nb[kk].w;
            float d2 = dx * dx + dy * dy + dz * dz + dw * dw;
            #pragma unroll
            for (int o = 32; o; o >>= 1) d2 += __shfl_xor(d2, o);   // uniform in wave
            const float e = __expf(-d2);
            p.x += e * nb[kk].x; p.y += e * nb[kk].y;
            p.z += e * nb[kk].z; p.w += e * nb[kk].w;
            S += e;
        }
    }

    const float rS = 1.f / S;
    float4 o4;
    o4.x = p.x * rS; o4.y = p.y * rS; o4.z = p.z * rS; o4.w = p.w * rS;
    *(float4*)&out[(size_t)n * XD + gcol] = o4;
}

extern "C" void kernel_launch(void* const* d_in, const int* in_sizes, int n_in,
                              void* d_out, int out_size, void* d_ws, size_t ws_size,
                              hipStream_t stream) {
    const float* x     = (const float*)d_in[0];
    const float* W1    = (const float*)d_in[1];
    const float* a1    = (const float*)d_in[2];
    const float* W2    = (const float*)d_in[3];
    const float* a2    = (const float*)d_in[4];
    const int*   graph = (const int*)d_in[5];
    float* out = (float*)d_out;
    float* t   = (float*)d_ws;          // needs N*512*4 = 20.48 MB of workspace

    dim3 grid1((N_NODES + 63) / 64, 2);               // (157, 2)
    gemm_mfma<<<grid1, 256, 0, stream>>>(x, W1, a1, W2, a2, t);

    gat_aggregate<<<5000, 256, 0, stream>>>(t, graph, out);
}

// Round 7
// 185.106 us; speedup vs baseline: 1.0011x; 1.0011x over previous
//
#include <hip/hip_runtime.h>
#include <math.h>

// Problem constants (from reference)
#define N_NODES 10000
#define K_NB    32
#define D       256    // per-group input/output feature dim
#define XD      512    // x / t / out row stride (2 groups concatenated)

typedef __attribute__((ext_vector_type(8))) short  short8;  // 8 bf16 (4 VGPR) MFMA A/B frag
typedef __attribute__((ext_vector_type(4))) float  f32x4;   // MFMA C/D frag

__device__ __forceinline__ float clip1(float v) { return fminf(fmaxf(v, -1.f), 1.f); }

__device__ __forceinline__ unsigned int bf16_rne(float f) {   // RNE f32 -> bf16 bits
    unsigned int u = __float_as_uint(f);
    return (u + 0x7FFFu + ((u >> 16) & 1u)) >> 16;
}
__device__ __forceinline__ float bf16f(unsigned int h) { return __uint_as_float(h << 16); }

// 8 consecutive-k fp32 -> hi/lo bf16 (Markidis split), packed 8x bf16 per uint4
__device__ __forceinline__ void cvt8(float4 A, float4 B, uint4& hi, uint4& lo) {
    const float v[8] = {A.x, A.y, A.z, A.w, B.x, B.y, B.z, B.w};
    unsigned int h[8], q[8];
    #pragma unroll
    for (int i = 0; i < 8; ++i) {
        h[i] = bf16_rne(v[i]);
        q[i] = bf16_rne(v[i] - bf16f(h[i]));
    }
    hi = make_uint4(h[0] | (h[1] << 16), h[2] | (h[3] << 16),
                    h[4] | (h[5] << 16), h[6] | (h[7] << 16));
    lo = make_uint4(q[0] | (q[1] << 16), q[2] | (q[3] << 16),
                    q[4] | (q[5] << 16), q[6] | (q[7] << 16));
}

// Kernel 0: one-time W -> bf16 hi/lo split (2 groups x 256x256, 8 elems/thread).
// Whi/Wlo are row-major bf16 [group][256][256]; 64 blocks x 256 thr.
__global__ __launch_bounds__(256)
void conv_w(const float* __restrict__ W1, const float* __restrict__ W2,
            unsigned short* __restrict__ Whi, unsigned short* __restrict__ Wlo)
{
    const int u    = blockIdx.x * 256 + threadIdx.x;   // 0..16383 (oct index)
    const int gidx = u >> 13;                          // 8192 octs per group
    const int rem  = u & 8191;
    const float* __restrict__ W = gidx ? W2 : W1;
    const float4 f0 = *(const float4*)&W[rem * 8];
    const float4 f1 = *(const float4*)&W[rem * 8 + 4];
    uint4 hi, lo;
    cvt8(f0, f1, hi, lo);
    *(uint4*)&Whi[gidx * 65536 + rem * 8] = hi;
    *(uint4*)&Wlo[gidx * 65536 + rem * 8] = lo;
}

// Kernel 1: t[row][g*256+o] = clip( (x_g @ W^T)[row][o] * softmax(a)[o], -1, 1 )
// Split-precision bf16 MFMA: out ~= xh*wh + xl*wh + xh*wl (xl*wl dropped).
// No LDS staging: B fragments load directly from pre-converted Whi/Wlo
// (L2-resident, per-lane 16B: row = nt*16+(l&15), k = kc*32+8*(l>>4));
// A slab converted on the fly (~40 VALU / chunk / wave).
// Wave = 16 rows x 4 col-tiles; grid (625, 2) x 4 waves = 5000 waves
// (~4.9/SIMD) — fixes round-6's 1.2 waves/SIMD starvation.
// 10000 = 625*16 exactly -> no row bounds checks.
// k-slot map identical for A and B -> contraction correct for any consistent
// slot bijection; C/D map is the m89-verified col=lane&15, row=(lane>>4)*4+reg.
__global__ __launch_bounds__(256, 4)
void gemm_mfma(const float* __restrict__ x,
               const float* __restrict__ a1, const float* __restrict__ a2,
               const unsigned short* __restrict__ Whi,
               const unsigned short* __restrict__ Wlo,
               float* __restrict__ t)
{
    const int g = blockIdx.y;
    const float* __restrict__ a = g ? a2 : a1;
    const int slab = blockIdx.x;            // 16-row slab, 0..624
    const int tid = threadIdx.x;
    const int w   = tid >> 6;
    const int l   = tid & 63;

    __shared__ float fwL[D];
    __shared__ float red[16];

    // ---- softmax(a) over 256 (block == 256 threads), redundantly per block ----
    {
        float v = a[tid];
        float m = v;
        #pragma unroll
        for (int o = 32; o; o >>= 1) m = fmaxf(m, __shfl_xor(m, o));
        if ((tid & 63) == 0) red[tid >> 6] = m;
        __syncthreads();
        m = fmaxf(fmaxf(red[0], red[1]), fmaxf(red[2], red[3]));
        float e = expf(v - m);
        float s = e;
        #pragma unroll
        for (int o = 32; o; o >>= 1) s += __shfl_xor(s, o);
        if ((tid & 63) == 0) red[4 + (tid >> 6)] = s;
        __syncthreads();
        s = red[4] + red[5] + red[6] + red[7];
        fwL[tid] = e / s;
    }
    __syncthreads();                         // fwL visible to all waves (epilogue)

    const unsigned short* __restrict__ WhiG = Whi + (g << 16);
    const unsigned short* __restrict__ WloG = Wlo + (g << 16);

    f32x4 acc[4];
    #pragma unroll
    for (int i = 0; i < 4; ++i) acc[i] = (f32x4){0.f, 0.f, 0.f, 0.f};

    const int arow = slab * 16 + (l & 15);   // this lane's A row
    const int koff = 8 * (l >> 4);           // this lane's k-slot base
    const int nt0  = w * 4;                  // this wave's 4 col-tiles

    for (int kc = 0; kc < 8; ++kc) {
        const int kbase = kc * 32 + koff;
        const float* xp = &x[(size_t)arow * XD + g * D + kbase];
        const float4 xa = *(const float4*)&xp[0];
        const float4 xb = *(const float4*)&xp[4];
        uint4 ahi, alo;
        cvt8(xa, xb, ahi, alo);
        const short8 ah = __builtin_bit_cast(short8, ahi);
        const short8 al = __builtin_bit_cast(short8, alo);

        #pragma unroll
        for (int i = 0; i < 4; ++i) {
            const int brow = (nt0 + i) * 16 + (l & 15);
            const short8 bh = __builtin_bit_cast(short8, *(const uint4*)&WhiG[brow * 256 + kbase]);
            const short8 bl = __builtin_bit_cast(short8, *(const uint4*)&WloG[brow * 256 + kbase]);
            acc[i] = __builtin_amdgcn_mfma_f32_16x16x32_bf16(ah, bh, acc[i], 0, 0, 0);
            acc[i] = __builtin_amdgcn_mfma_f32_16x16x32_bf16(al, bh, acc[i], 0, 0, 0);
            acc[i] = __builtin_amdgcn_mfma_f32_16x16x32_bf16(ah, bl, acc[i], 0, 0, 0);
        }
    }

    // ---- epilogue: fw scale + hardtanh + store (C/D: col=l&15, row=(l>>4)*4+r) ----
    #pragma unroll
    for (int i = 0; i < 4; ++i) {
        const int   col = (nt0 + i) * 16 + (l & 15);
        const float fw  = fwL[col];
        #pragma unroll
        for (int r = 0; r < 4; ++r) {
            const int row = slab * 16 + (l >> 4) * 4 + r;
            t[(size_t)row * XD + g * D + col] = clip1(acc[i][r] * fw);
        }
    }
}

// Kernel 2: SINGLE-PASS gather + Gaussian attention + aggregation
// (round-5 structure — 4 waves share one (n,g); 80000 waves total for TLP).
//   out_n = sum_k exp(-d2_k) * nb_k / sum_k exp(-d2_k)
// Max-subtract dropped: t is softmax(a)-feature-scaled (fw ~ 1/256) ->
// d2 ~ 0.02 << 88, exp can't underflow; identical math to reference softmax.
// launch_bounds (256,8): VGPR 32, LDS 4.6KB -> 8 blocks/CU = 100% occupancy
// (round 5 was capped at 74% with min-waves 6).
__global__ __launch_bounds__(256, 8)
void gat_aggregate(const float* __restrict__ t, const int* __restrict__ graph,
                   float* __restrict__ out)
{
    const int n   = blockIdx.x;
    const int g   = blockIdx.y;
    const int tid = threadIdx.x;
    const int w   = tid >> 6;
    const int l   = tid & 63;

    __shared__ float part[4][D];    // per-wave partial weighted sums (4 KB)
    __shared__ float Ssh[4];        // per-wave partial exp-sums

    // neighbor indices for this wave's 8 k's (wave-uniform -> scalar loads)
    int rows[8];
    #pragma unroll
    for (int kk = 0; kk < 8; ++kk)
        rows[kk] = graph[(size_t)n * K_NB + (w + kk * 4)];

    const size_t gcol = (size_t)g * D + 4 * l;
    const float4 own4 = *(const float4*)&t[(size_t)n * XD + gcol];

    // batch all 8 gather loads before any use (8 outstanding float4 / lane)
    float4 nb[8];
    #pragma unroll
    for (int kk = 0; kk < 8; ++kk)
        nb[kk] = *(const float4*)&t[(size_t)rows[kk] * XD + gcol];

    // single pass: distance reduce -> e -> weighted accumulate; nb[kk] dies here
    float4 p = make_float4(0.f, 0.f, 0.f, 0.f);
    float  S = 0.f;
    #pragma unroll
    for (int kk = 0; kk < 8; ++kk) {
        const float dx = own4.x - nb[kk].x, dy = own4.y - nb[kk].y;
        const float dz = own4.z - nb[kk].z, dw = own4.w - nb[kk].w;
        float d2 = dx * dx + dy * dy + dz * dz + dw * dw;
        #pragma unroll
        for (int o = 32; o; o >>= 1) d2 += __shfl_xor(d2, o);   // all 64 lanes uniform
        const float e = __expf(-d2);
        p.x += e * nb[kk].x; p.y += e * nb[kk].y;
        p.z += e * nb[kk].z; p.w += e * nb[kk].w;
        S += e;
    }

    *(float4*)&part[w][4 * l] = p;   // float4 stride-16B: 2-way bank alias (free)
    if (l == 0) Ssh[w] = S;
    __syncthreads();

    const float rS = 1.f / (Ssh[0] + Ssh[1] + Ssh[2] + Ssh[3]);
    const float y  = (part[0][tid] + part[1][tid] + part[2][tid] + part[3][tid]) * rS;
    out[(size_t)n * XD + (size_t)g * D + tid] = y;
}

extern "C" void kernel_launch(void* const* d_in, const int* in_sizes, int n_in,
                              void* d_out, int out_size, void* d_ws, size_t ws_size,
                              hipStream_t stream) {
    const float* x     = (const float*)d_in[0];
    const float* W1    = (const float*)d_in[1];
    const float* a1    = (const float*)d_in[2];
    const float* W2    = (const float*)d_in[3];
    const float* a2    = (const float*)d_in[4];
    const int*   graph = (const int*)d_in[5];
    float* out = (float*)d_out;

    // workspace layout: t (20.48 MB) | Whi (256 KB) | Wlo (256 KB)
    float*          t   = (float*)d_ws;
    unsigned short* Whi = (unsigned short*)((char*)d_ws + (size_t)N_NODES * XD * 4);
    unsigned short* Wlo = Whi + 2 * 65536;

    conv_w<<<64, 256, 0, stream>>>(W1, W2, Whi, Wlo);

    dim3 grid1(N_NODES / 16, 2);                      // (625, 2)
    gemm_mfma<<<grid1, 256, 0, stream>>>(x, a1, a2, Whi, Wlo, t);

    dim3 grid2(N_NODES, 2);
    gat_aggregate<<<grid2, 256, 0, stream>>>(t, graph, out);
}

// Round 8
// 171.458 us; speedup vs baseline: 1.0808x; 1.0796x over previous
//
#include <hip/hip_runtime.h>
#include <math.h>

// Problem constants (from reference)
#define N_NODES 10000
#define K_NB    32
#define D       256    // per-group input/output feature dim
#define XD      512    // x / t / out row stride (2 groups concatenated)

typedef __attribute__((ext_vector_type(8))) short  short8;  // 8 bf16 (4 VGPR) MFMA A/B frag
typedef __attribute__((ext_vector_type(4))) float  f32x4;   // MFMA C/D frag

__device__ __forceinline__ float clip1(float v) { return fminf(fmaxf(v, -1.f), 1.f); }

__device__ __forceinline__ unsigned int bf16_rne(float f) {   // RNE f32 -> bf16 bits
    unsigned int u = __float_as_uint(f);
    return (u + 0x7FFFu + ((u >> 16) & 1u)) >> 16;
}
__device__ __forceinline__ float bf16f(unsigned int h) { return __uint_as_float(h << 16); }
__device__ __forceinline__ float blo(unsigned int u) { return __uint_as_float(u << 16); }
__device__ __forceinline__ float bhif(unsigned int u) { return __uint_as_float(u & 0xFFFF0000u); }

// 8 consecutive-k fp32 -> hi/lo bf16 (Markidis split), packed 8x bf16 per uint4
__device__ __forceinline__ void cvt8(float4 A, float4 B, uint4& hi, uint4& lo) {
    const float v[8] = {A.x, A.y, A.z, A.w, B.x, B.y, B.z, B.w};
    unsigned int h[8], q[8];
    #pragma unroll
    for (int i = 0; i < 8; ++i) {
        h[i] = bf16_rne(v[i]);
        q[i] = bf16_rne(v[i] - bf16f(h[i]));
    }
    hi = make_uint4(h[0] | (h[1] << 16), h[2] | (h[3] << 16),
                    h[4] | (h[5] << 16), h[6] | (h[7] << 16));
    lo = make_uint4(q[0] | (q[1] << 16), q[2] | (q[3] << 16),
                    q[4] | (q[5] << 16), q[6] | (q[7] << 16));
}

// Kernel 0: one-time W -> bf16 hi/lo split (2 groups x 256x256, 8 elems/thread).
__global__ __launch_bounds__(256)
void conv_w(const float* __restrict__ W1, const float* __restrict__ W2,
            unsigned short* __restrict__ Whi, unsigned short* __restrict__ Wlo)
{
    const int u    = blockIdx.x * 256 + threadIdx.x;   // 0..16383 (oct index)
    const int gidx = u >> 13;                          // 8192 octs per group
    const int rem  = u & 8191;
    const float* __restrict__ W = gidx ? W2 : W1;
    const float4 f0 = *(const float4*)&W[rem * 8];
    const float4 f1 = *(const float4*)&W[rem * 8 + 4];
    uint4 hi, lo;
    cvt8(f0, f1, hi, lo);
    *(uint4*)&Whi[gidx * 65536 + rem * 8] = hi;
    *(uint4*)&Wlo[gidx * 65536 + rem * 8] = lo;
}

// Kernel 1: t16[row][g*256+o] = bf16( clip( (x_g@W^T)[row][o]*softmax(a)[o] ) )
// Split-precision bf16 MFMA: out ~= xh*wh + xl*wh + xh*wl (xl*wl dropped).
// Structure identical to round 7 (attribution-clean) except the OUTPUT t is
// now bf16 (halves gat's gather bytes; write traffic 20->10 MB).
// Wave = 16 rows x 4 col-tiles; grid (625,2) x 4 waves = 5000 waves (~4.9/SIMD).
// C/D map: m89-verified col=lane&15, row=(lane>>4)*4+reg (validated rounds 6/7).
__global__ __launch_bounds__(256, 4)
void gemm_mfma(const float* __restrict__ x,
               const float* __restrict__ a1, const float* __restrict__ a2,
               const unsigned short* __restrict__ Whi,
               const unsigned short* __restrict__ Wlo,
               unsigned short* __restrict__ t16)
{
    const int g = blockIdx.y;
    const float* __restrict__ a = g ? a2 : a1;
    const int slab = blockIdx.x;            // 16-row slab, 0..624
    const int tid = threadIdx.x;
    const int w   = tid >> 6;
    const int l   = tid & 63;

    __shared__ float fwL[D];
    __shared__ float red[16];

    // ---- softmax(a) over 256 (block == 256 threads), redundantly per block ----
    {
        float v = a[tid];
        float m = v;
        #pragma unroll
        for (int o = 32; o; o >>= 1) m = fmaxf(m, __shfl_xor(m, o));
        if ((tid & 63) == 0) red[tid >> 6] = m;
        __syncthreads();
        m = fmaxf(fmaxf(red[0], red[1]), fmaxf(red[2], red[3]));
        float e = expf(v - m);
        float s = e;
        #pragma unroll
        for (int o = 32; o; o >>= 1) s += __shfl_xor(s, o);
        if ((tid & 63) == 0) red[4 + (tid >> 6)] = s;
        __syncthreads();
        s = red[4] + red[5] + red[6] + red[7];
        fwL[tid] = e / s;
    }
    __syncthreads();                         // fwL visible to all waves (epilogue)

    const unsigned short* __restrict__ WhiG = Whi + (g << 16);
    const unsigned short* __restrict__ WloG = Wlo + (g << 16);

    f32x4 acc[4];
    #pragma unroll
    for (int i = 0; i < 4; ++i) acc[i] = (f32x4){0.f, 0.f, 0.f, 0.f};

    const int arow = slab * 16 + (l & 15);   // this lane's A row
    const int koff = 8 * (l >> 4);           // this lane's k-slot base
    const int nt0  = w * 4;                  // this wave's 4 col-tiles

    for (int kc = 0; kc < 8; ++kc) {
        const int kbase = kc * 32 + koff;
        const float* xp = &x[(size_t)arow * XD + g * D + kbase];
        const float4 xa = *(const float4*)&xp[0];
        const float4 xb = *(const float4*)&xp[4];
        uint4 ahi, alo;
        cvt8(xa, xb, ahi, alo);
        const short8 ah = __builtin_bit_cast(short8, ahi);
        const short8 al = __builtin_bit_cast(short8, alo);

        #pragma unroll
        for (int i = 0; i < 4; ++i) {
            const int brow = (nt0 + i) * 16 + (l & 15);
            const short8 bh = __builtin_bit_cast(short8, *(const uint4*)&WhiG[brow * 256 + kbase]);
            const short8 bl = __builtin_bit_cast(short8, *(const uint4*)&WloG[brow * 256 + kbase]);
            acc[i] = __builtin_amdgcn_mfma_f32_16x16x32_bf16(ah, bh, acc[i], 0, 0, 0);
            acc[i] = __builtin_amdgcn_mfma_f32_16x16x32_bf16(al, bh, acc[i], 0, 0, 0);
            acc[i] = __builtin_amdgcn_mfma_f32_16x16x32_bf16(ah, bl, acc[i], 0, 0, 0);
        }
    }

    // ---- epilogue: fw scale + hardtanh + bf16 store ----
    #pragma unroll
    for (int i = 0; i < 4; ++i) {
        const int   col = (nt0 + i) * 16 + (l & 15);
        const float fw  = fwL[col];
        #pragma unroll
        for (int r = 0; r < 4; ++r) {
            const int row = slab * 16 + (l >> 4) * 4 + r;
            t16[(size_t)row * XD + g * D + col] =
                (unsigned short)bf16_rne(clip1(acc[i][r] * fw));
        }
    }
}

// Kernel 2: SINGLE-PASS gather + Gaussian attention + aggregation, bf16 t.
// Round-7 structure (4 waves share one (n,g); 80000 waves for TLP); only the
// t loads change: 8B uint2 = 4 bf16 per lane (halves gather bytes; working
// set 20.5 -> 10.2 MB, better L2 hit).  Compute stays fp32.
//   out_n = sum_k exp(-d2_k) * nb_k / sum_k exp(-d2_k)
// Max-subtract dropped: d2 ~ 0.02 << 88, exp can't underflow.
__global__ __launch_bounds__(256, 8)
void gat_aggregate(const unsigned short* __restrict__ t16,
                   const int* __restrict__ graph, float* __restrict__ out)
{
    const int n   = blockIdx.x;
    const int g   = blockIdx.y;
    const int tid = threadIdx.x;
    const int w   = tid >> 6;
    const int l   = tid & 63;

    __shared__ float part[4][D];    // per-wave partial weighted sums (4 KB)
    __shared__ float Ssh[4];        // per-wave partial exp-sums

    int rows[8];
    #pragma unroll
    for (int kk = 0; kk < 8; ++kk)
        rows[kk] = graph[(size_t)n * K_NB + (w + kk * 4)];

    const size_t gcol = (size_t)g * D + 4 * l;           // bf16 element index
    const uint2 ov = *(const uint2*)&t16[(size_t)n * XD + gcol];
    const float o0 = blo(ov.x), o1 = bhif(ov.x), o2 = blo(ov.y), o3 = bhif(ov.y);

    // batch all 8 gather loads before any use (8 outstanding 8B / lane)
    uint2 nbu[8];
    #pragma unroll
    for (int kk = 0; kk < 8; ++kk)
        nbu[kk] = *(const uint2*)&t16[(size_t)rows[kk] * XD + gcol];

    float4 p = make_float4(0.f, 0.f, 0.f, 0.f);
    float  S = 0.f;
    #pragma unroll
    for (int kk = 0; kk < 8; ++kk) {
        const float n0 = blo(nbu[kk].x), n1 = bhif(nbu[kk].x);
        const float n2 = blo(nbu[kk].y), n3 = bhif(nbu[kk].y);
        const float dx = o0 - n0, dy = o1 - n1, dz = o2 - n2, dw = o3 - n3;
        float d2 = dx * dx + dy * dy + dz * dz + dw * dw;
        #pragma unroll
        for (int o = 32; o; o >>= 1) d2 += __shfl_xor(d2, o);   // uniform in wave
        const float e = __expf(-d2);
        p.x += e * n0; p.y += e * n1; p.z += e * n2; p.w += e * n3;
        S += e;
    }

    *(float4*)&part[w][4 * l] = p;
    if (l == 0) Ssh[w] = S;
    __syncthreads();

    const float rS = 1.f / (Ssh[0] + Ssh[1] + Ssh[2] + Ssh[3]);
    const float y  = (part[0][tid] + part[1][tid] + part[2][tid] + part[3][tid]) * rS;
    out[(size_t)n * XD + (size_t)g * D + tid] = y;
}

extern "C" void kernel_launch(void* const* d_in, const int* in_sizes, int n_in,
                              void* d_out, int out_size, void* d_ws, size_t ws_size,
                              hipStream_t stream) {
    const float* x     = (const float*)d_in[0];
    const float* W1    = (const float*)d_in[1];
    const float* a1    = (const float*)d_in[2];
    const float* W2    = (const float*)d_in[3];
    const float* a2    = (const float*)d_in[4];
    const int*   graph = (const int*)d_in[5];
    float* out = (float*)d_out;

    // workspace layout: t16 bf16 (10.24 MB) | Whi (256 KB) | Wlo (256 KB)
    unsigned short* t16 = (unsigned short*)d_ws;
    unsigned short* Whi = t16 + (size_t)N_NODES * XD;
    unsigned short* Wlo = Whi + 2 * 65536;

    conv_w<<<64, 256, 0, stream>>>(W1, W2, Whi, Wlo);

    dim3 grid1(N_NODES / 16, 2);                      // (625, 2)
    gemm_mfma<<<grid1, 256, 0, stream>>>(x, a1, a2, Whi, Wlo, t16);

    dim3 grid2(N_NODES, 2);
    gat_aggregate<<<grid2, 256, 0, stream>>>(t16, graph, out);
}

// Round 9
// 154.742 us; speedup vs baseline: 1.1976x; 1.1080x over previous
//
#include <hip/hip_runtime.h>
#include <math.h>

// Problem constants (from reference)
#define N_NODES 10000
#define K_NB    32
#define D       256    // per-group input/output feature dim
#define XD      512    // x / t / out row stride (2 groups concatenated)

typedef __attribute__((ext_vector_type(8))) short  short8;  // 8 bf16 (4 VGPR) MFMA A/B frag
typedef __attribute__((ext_vector_type(4))) float  f32x4;   // MFMA C/D frag

__device__ __forceinline__ float clip1(float v) { return fminf(fmaxf(v, -1.f), 1.f); }

__device__ __forceinline__ unsigned int bf16_rne(float f) {   // RNE f32 -> bf16 bits
    unsigned int u = __float_as_uint(f);
    return (u + 0x7FFFu + ((u >> 16) & 1u)) >> 16;
}
__device__ __forceinline__ float bf16f(unsigned int h) { return __uint_as_float(h << 16); }
__device__ __forceinline__ float blo(unsigned int u) { return __uint_as_float(u << 16); }
__device__ __forceinline__ float bhif(unsigned int u) { return __uint_as_float(u & 0xFFFF0000u); }

// 8 consecutive-k fp32 -> hi/lo bf16 (Markidis split), packed 8x bf16 per uint4
__device__ __forceinline__ void cvt8(float4 A, float4 B, uint4& hi, uint4& lo) {
    const float v[8] = {A.x, A.y, A.z, A.w, B.x, B.y, B.z, B.w};
    unsigned int h[8], q[8];
    #pragma unroll
    for (int i = 0; i < 8; ++i) {
        h[i] = bf16_rne(v[i]);
        q[i] = bf16_rne(v[i] - bf16f(h[i]));
    }
    hi = make_uint4(h[0] | (h[1] << 16), h[2] | (h[3] << 16),
                    h[4] | (h[5] << 16), h[6] | (h[7] << 16));
    lo = make_uint4(q[0] | (q[1] << 16), q[2] | (q[3] << 16),
                    q[4] | (q[5] << 16), q[6] | (q[7] << 16));
}

// Kernel 0: one-time W -> bf16 hi/lo split (2 groups x 256x256, 8 elems/thread).
__global__ __launch_bounds__(256)
void conv_w(const float* __restrict__ W1, const float* __restrict__ W2,
            unsigned short* __restrict__ Whi, unsigned short* __restrict__ Wlo)
{
    const int u    = blockIdx.x * 256 + threadIdx.x;   // 0..16383 (oct index)
    const int gidx = u >> 13;                          // 8192 octs per group
    const int rem  = u & 8191;
    const float* __restrict__ W = gidx ? W2 : W1;
    const float4 f0 = *(const float4*)&W[rem * 8];
    const float4 f1 = *(const float4*)&W[rem * 8 + 4];
    uint4 hi, lo;
    cvt8(f0, f1, hi, lo);
    *(uint4*)&Whi[gidx * 65536 + rem * 8] = hi;
    *(uint4*)&Wlo[gidx * 65536 + rem * 8] = lo;
}

// Kernel 1: t16[row][g*256+o] = bf16( clip( (x_g@W^T)[row][o]*softmax(a)[o] ) )
// BYTE-IDENTICAL to round 8 (attribution: only gat changes this round).
__global__ __launch_bounds__(256, 4)
void gemm_mfma(const float* __restrict__ x,
               const float* __restrict__ a1, const float* __restrict__ a2,
               const unsigned short* __restrict__ Whi,
               const unsigned short* __restrict__ Wlo,
               unsigned short* __restrict__ t16)
{
    const int g = blockIdx.y;
    const float* __restrict__ a = g ? a2 : a1;
    const int slab = blockIdx.x;            // 16-row slab, 0..624
    const int tid = threadIdx.x;
    const int w   = tid >> 6;
    const int l   = tid & 63;

    __shared__ float fwL[D];
    __shared__ float red[16];

    // ---- softmax(a) over 256 (block == 256 threads), redundantly per block ----
    {
        float v = a[tid];
        float m = v;
        #pragma unroll
        for (int o = 32; o; o >>= 1) m = fmaxf(m, __shfl_xor(m, o));
        if ((tid & 63) == 0) red[tid >> 6] = m;
        __syncthreads();
        m = fmaxf(fmaxf(red[0], red[1]), fmaxf(red[2], red[3]));
        float e = expf(v - m);
        float s = e;
        #pragma unroll
        for (int o = 32; o; o >>= 1) s += __shfl_xor(s, o);
        if ((tid & 63) == 0) red[4 + (tid >> 6)] = s;
        __syncthreads();
        s = red[4] + red[5] + red[6] + red[7];
        fwL[tid] = e / s;
    }
    __syncthreads();                         // fwL visible to all waves (epilogue)

    const unsigned short* __restrict__ WhiG = Whi + (g << 16);
    const unsigned short* __restrict__ WloG = Wlo + (g << 16);

    f32x4 acc[4];
    #pragma unroll
    for (int i = 0; i < 4; ++i) acc[i] = (f32x4){0.f, 0.f, 0.f, 0.f};

    const int arow = slab * 16 + (l & 15);   // this lane's A row
    const int koff = 8 * (l >> 4);           // this lane's k-slot base
    const int nt0  = w * 4;                  // this wave's 4 col-tiles

    for (int kc = 0; kc < 8; ++kc) {
        const int kbase = kc * 32 + koff;
        const float* xp = &x[(size_t)arow * XD + g * D + kbase];
        const float4 xa = *(const float4*)&xp[0];
        const float4 xb = *(const float4*)&xp[4];
        uint4 ahi, alo;
        cvt8(xa, xb, ahi, alo);
        const short8 ah = __builtin_bit_cast(short8, ahi);
        const short8 al = __builtin_bit_cast(short8, alo);

        #pragma unroll
        for (int i = 0; i < 4; ++i) {
            const int brow = (nt0 + i) * 16 + (l & 15);
            const short8 bh = __builtin_bit_cast(short8, *(const uint4*)&WhiG[brow * 256 + kbase]);
            const short8 bl = __builtin_bit_cast(short8, *(const uint4*)&WloG[brow * 256 + kbase]);
            acc[i] = __builtin_amdgcn_mfma_f32_16x16x32_bf16(ah, bh, acc[i], 0, 0, 0);
            acc[i] = __builtin_amdgcn_mfma_f32_16x16x32_bf16(al, bh, acc[i], 0, 0, 0);
            acc[i] = __builtin_amdgcn_mfma_f32_16x16x32_bf16(ah, bl, acc[i], 0, 0, 0);
        }
    }

    // ---- epilogue: fw scale + hardtanh + bf16 store ----
    #pragma unroll
    for (int i = 0; i < 4; ++i) {
        const int   col = (nt0 + i) * 16 + (l & 15);
        const float fw  = fwL[col];
        #pragma unroll
        for (int r = 0; r < 4; ++r) {
            const int row = slab * 16 + (l >> 4) * 4 + r;
            t16[(size_t)row * XD + g * D + col] =
                (unsigned short)bf16_rne(clip1(acc[i][r] * fw));
        }
    }
}

// Kernel 2: SINGLE-PASS gather + Gaussian attention + aggregation, bf16 t.
// Round-8 structure; the 64-lane reduction is restructured from per-k
// butterfly (48 shfl + 48 add + 8 exp per wave, all wave-uniform-redundant)
// to REDUCE-SCATTER: 3 select+shfl+add steps leave lane l owning k=l&7,
// 3 butterfly steps finish the 64-lane sum, ONE exp per lane, 3-step
// butterfly for the wave's S, and 8 ds_bpermute gathers (LDS pipe, off the
// VALU) feed the weighted accumulate.  ~27 shfl/add + 1 exp vs 96 + 8 exp.
//   out_n = sum_k exp(-d2_k) * nb_k / sum_k exp(-d2_k)
// Max-subtract dropped: d2 ~ 0.02 << 88, exp can't underflow.
__global__ __launch_bounds__(256, 8)
void gat_aggregate(const unsigned short* __restrict__ t16,
                   const int* __restrict__ graph, float* __restrict__ out)
{
    const int n   = blockIdx.x;
    const int g   = blockIdx.y;
    const int tid = threadIdx.x;
    const int w   = tid >> 6;
    const int l   = tid & 63;

    __shared__ float part[4][D];    // per-wave partial weighted sums (4 KB)
    __shared__ float Ssh[4];        // per-wave partial exp-sums

    int rows[8];
    #pragma unroll
    for (int kk = 0; kk < 8; ++kk)
        rows[kk] = graph[(size_t)n * K_NB + (w + kk * 4)];

    const size_t gcol = (size_t)g * D + 4 * l;           // bf16 element index
    const uint2 ov = *(const uint2*)&t16[(size_t)n * XD + gcol];
    const float o0 = blo(ov.x), o1 = bhif(ov.x), o2 = blo(ov.y), o3 = bhif(ov.y);

    // batch all 8 gather loads before any use (8 outstanding 8B / lane)
    uint2 nbu[8];
    #pragma unroll
    for (int kk = 0; kk < 8; ++kk)
        nbu[kk] = *(const uint2*)&t16[(size_t)rows[kk] * XD + gcol];

    // unpack once; per-lane partial d2 for each of this wave's 8 k's
    float nf[8][4];
    float d2p[8];
    #pragma unroll
    for (int kk = 0; kk < 8; ++kk) {
        nf[kk][0] = blo(nbu[kk].x); nf[kk][1] = bhif(nbu[kk].x);
        nf[kk][2] = blo(nbu[kk].y); nf[kk][3] = bhif(nbu[kk].y);
        const float dx = o0 - nf[kk][0], dy = o1 - nf[kk][1];
        const float dz = o2 - nf[kk][2], dw = o3 - nf[kk][3];
        d2p[kk] = dx * dx + dy * dy + dz * dz + dw * dw;
    }

    // reduce-scatter over lane bits 0..2: lane l ends owning kk = l&7
    const bool b0 = l & 1, b1 = l & 2, b2 = l & 4;
    float u[4];
    #pragma unroll
    for (int i = 0; i < 4; ++i) {
        const float give = b0 ? d2p[2 * i] : d2p[2 * i + 1];
        const float keep = b0 ? d2p[2 * i + 1] : d2p[2 * i];
        u[i] = keep + __shfl_xor(give, 1);
    }
    float v[2];
    #pragma unroll
    for (int i = 0; i < 2; ++i) {
        const float give = b1 ? u[2 * i] : u[2 * i + 1];
        const float keep = b1 ? u[2 * i + 1] : u[2 * i];
        v[i] = keep + __shfl_xor(give, 2);
    }
    float d2 = (b2 ? v[1] : v[0]) + __shfl_xor(b2 ? v[0] : v[1], 4);
    // finish the 64-lane sum (kk = l&7 fixed, sum over the 8 lane-groups)
    d2 += __shfl_xor(d2, 8);
    d2 += __shfl_xor(d2, 16);
    d2 += __shfl_xor(d2, 32);

    const float e = __expf(-d2);          // ONE exp per lane (owns kk = l&7)

    // wave's exp-sum over its 8 k's (uniform in all lanes after 3 steps)
    float Sw = e;
    Sw += __shfl_xor(Sw, 1);
    Sw += __shfl_xor(Sw, 2);
    Sw += __shfl_xor(Sw, 4);

    // gather the 8 e's (ds_bpermute — LDS pipe) and accumulate
    const int base = l & 56;
    float4 p = make_float4(0.f, 0.f, 0.f, 0.f);
    #pragma unroll
    for (int kk = 0; kk < 8; ++kk) {
        const float ak = __shfl(e, base + kk);
        p.x += ak * nf[kk][0]; p.y += ak * nf[kk][1];
        p.z += ak * nf[kk][2]; p.w += ak * nf[kk][3];
    }

    *(float4*)&part[w][4 * l] = p;
    if (l == 0) Ssh[w] = Sw;
    __syncthreads();

    const float rS = 1.f / (Ssh[0] + Ssh[1] + Ssh[2] + Ssh[3]);
    const float y  = (part[0][tid] + part[1][tid] + part[2][tid] + part[3][tid]) * rS;
    out[(size_t)n * XD + (size_t)g * D + tid] = y;
}

extern "C" void kernel_launch(void* const* d_in, const int* in_sizes, int n_in,
                              void* d_out, int out_size, void* d_ws, size_t ws_size,
                              hipStream_t stream) {
    const float* x     = (const float*)d_in[0];
    const float* W1    = (const float*)d_in[1];
    const float* a1    = (const float*)d_in[2];
    const float* W2    = (const float*)d_in[3];
    const float* a2    = (const float*)d_in[4];
    const int*   graph = (const int*)d_in[5];
    float* out = (float*)d_out;

    // workspace layout: t16 bf16 (10.24 MB) | Whi (256 KB) | Wlo (256 KB)
    unsigned short* t16 = (unsigned short*)d_ws;
    unsigned short* Whi = t16 + (size_t)N_NODES * XD;
    unsigned short* Wlo = Whi + 2 * 65536;

    conv_w<<<64, 256, 0, stream>>>(W1, W2, Whi, Wlo);

    dim3 grid1(N_NODES / 16, 2);                      // (625, 2)
    gemm_mfma<<<grid1, 256, 0, stream>>>(x, a1, a2, Whi, Wlo, t16);

    dim3 grid2(N_NODES, 2);
    gat_aggregate<<<grid2, 256, 0, stream>>>(t16, graph, out);
}